// Round 2
// baseline (306.046 us; speedup 1.0000x reference)
//
#include <hip/hip_runtime.h>

// LightLIF fused step on MI355X (gfx950) — round 6.
//
//   A = [inputs | z]            : [4096, 3072] fp32   (M x K)
//   Bm = [w_in ; w_rec*(1-eye)] : [3072, 2048] fp32   (K x N), B pre-scaled by 256
//   i_t = A @ Bm    (fp32-accurate via f16 Markidis split, 3 MFMA passes)
//   new_v = DECAY*v + (1-DECAY)*i_t - 0.615*z ; spike vs THR
//   d_out = [new_z (M*N) | new_v (M*N)]
//
// Round-6 (counters showed round-5's ds_read burst serializing with MFMA:
// MfmaUtil 40%, wall 4200cy/step vs LDS 1540 + MFMA 1862 ~ serial sum):
//  1. Register fragment double-buffer: during step kt's 48 MFMAs, prefetch
//     step kt+1's A-frags + B j=0 pair from the (already-resident) ring
//     buffer into a second register set. Post-barrier MFMAs start from
//     registers with zero LDS dependency. K-loop unrolled x2 for static
//     register rotation. vmcnt(0) at boundary drains only step-old loads.
//  2. prep_a + prep_b merged into one dispatch (one less launch gap).
//  Numerics bit-identical to rounds 4-5 (same MFMA order per accumulator).

#define M_DIM 4096
#define N_DIM 2048
#define K_DIM 3072
#define KA    1024
#define BK    32
#define NSTEP (K_DIM / BK)          // 96
#define AIMG  8192                  // halves: 4 k-octets x 256 rows x 8
#define BIMG  4096                  // halves: 4 k-octets x 128 cols x 8
#define BUF_HALVES (2 * AIMG + 2 * BIMG)  // 24576 halves = 48 KB per buffer
#define NBUF 3
#define LDS_BYTES (NBUF * BUF_HALVES * 2) // 147456 B = 144 KB

#define SZ_AH ((size_t)16 * 96 * AIMG * 2)  // 25,165,824 B (one of hi/lo)
#define SZ_BH ((size_t)16 * 96 * BIMG * 2)  // 12,582,912 B
#define WS_NEEDED (2 * SZ_AH + 2 * SZ_BH)   // 75,497,472 B

typedef _Float16 f16x8 __attribute__((ext_vector_type(8)));
typedef float    f32x4 __attribute__((ext_vector_type(4)));

#define GLOBAL_AS(p) ((const __attribute__((address_space(1))) void*)(p))
#define LDS_AS(p)    ((__attribute__((address_space(3))) void*)(p))

// hi/lo split with lo pre-scaled by 2048 (RNE conversions)
#define SPLIT(x, dsthi, dstlo, idx)                                  \
  {                                                                  \
    _Float16 _h = (_Float16)(x);                                     \
    float    _r = ((x) - (float)_h) * 2048.0f;                       \
    dsthi[idx] = _h;                                                 \
    dstlo[idx] = (_Float16)_r;                                       \
  }

// ---------------------------------------------------------------------------
// prep_ab: merged A-split and B-split. grid (96 kt, 16 bg), block 256.
// All 256 threads do the A work for (kt, bm=bg); threads 0..127 additionally
// do the B work for (kt, bn=bg). Same math/layout as rounds 4-5.
// ---------------------------------------------------------------------------
__global__ void prep_ab(const float* __restrict__ inputs,
                        const float* __restrict__ z,
                        const float* __restrict__ w_in,
                        const float* __restrict__ w_rec,
                        _Float16* __restrict__ ahi, _Float16* __restrict__ alo,
                        _Float16* __restrict__ bhi, _Float16* __restrict__ blo) {
  const int kt = blockIdx.x, bg = blockIdx.y;
  const int t = threadIdx.x;

  // ---- A part: [inputs|z] -> (hi,lo) f16 images, layout [kg][row 256][8]
  {
    const int s = t & 3;       // k-octet 0..3
    const int rr = t >> 2;     // 0..63
    const int k0 = kt * BK + s * 8;
    const size_t img = ((size_t)bg * 96 + kt) * AIMG;
#pragma unroll
    for (int p = 0; p < 4; ++p) {
      const int row = p * 64 + rr;
      const int rg = bg * 256 + row;
      const float* src = (kt < 32) ? inputs + (size_t)rg * KA + k0
                                   : z + (size_t)rg * N_DIM + (k0 - KA);
      const float4 f0 = *(const float4*)(src);
      const float4 f1 = *(const float4*)(src + 4);
      f16x8 hi, lo;
      SPLIT(f0.x, hi, lo, 0);
      SPLIT(f0.y, hi, lo, 1);
      SPLIT(f0.z, hi, lo, 2);
      SPLIT(f0.w, hi, lo, 3);
      SPLIT(f1.x, hi, lo, 4);
      SPLIT(f1.y, hi, lo, 5);
      SPLIT(f1.z, hi, lo, 6);
      SPLIT(f1.w, hi, lo, 7);
      const size_t o = img + (size_t)s * 2048 + (size_t)row * 8;
      *(f16x8*)&ahi[o] = hi;
      *(f16x8*)&alo[o] = lo;
    }
  }

  // ---- B part: w (x256, diag-masked) -> transposed images [kg][col 128][8]
  if (t < 128) {
    const int c = t;                // 0..127
    const int ng = bg * 128 + c;
    const int k0 = kt * BK;
    f16x8 hi[4], lo[4];
#pragma unroll
    for (int kk = 0; kk < BK; ++kk) {
      const int k = k0 + kk;
      float x = (k < KA) ? w_in[(size_t)k * N_DIM + ng]
                         : w_rec[(size_t)(k - KA) * N_DIM + ng];
      if (k >= KA && (k - KA) == ng) x = 0.0f;   // zero diagonal of w_rec
      x *= 256.0f;                               // keep hi-parts normal in f16
      SPLIT(x, hi[kk >> 3], lo[kk >> 3], kk & 7);
    }
    const size_t img = ((size_t)bg * 96 + kt) * BIMG + (size_t)c * 8;
#pragma unroll
    for (int q = 0; q < 4; ++q) {
      *(f16x8*)&bhi[img + (size_t)q * 1024] = hi[q];
      *(f16x8*)&blo[img + (size_t)q * 1024] = lo[q];
    }
  }
}

// ---------------------------------------------------------------------------
// GEMM + fused LIF epilogue. grid (16 bm, 16 bn), block 512 (8 waves, 4m x 2n
// of 64x64). 3-deep 144 KB LDS ring, distance-2 staging; register fragment
// double-buffer (next step's A + B0 read from LDS under current MFMAs);
// one vmcnt(0)+barrier per K-step; K-loop unrolled x2 for static reg rotation.
// ---------------------------------------------------------------------------
__global__ __launch_bounds__(512, 2) void lif_gemm(
    const _Float16* __restrict__ ahi, const _Float16* __restrict__ alo,
    const _Float16* __restrict__ bhi, const _Float16* __restrict__ blo,
    const float* __restrict__ vin, const float* __restrict__ zin,
    float* __restrict__ out) {
  extern __shared__ __align__(16) _Float16 sbuf[];  // NBUF * BUF_HALVES = 144 KB

  const int tid = threadIdx.x;
  const int bm = blockIdx.x;   // same-bm blocks share XCD -> A L2-local
  const int bn = blockIdx.y;
  const int lane = tid & 63;
  const int wid = tid >> 6;       // 0..7
  const int wm = wid & 3;         // m-quadrant (4 x 64)
  const int wn = wid >> 2;        // n-half (2 x 64)
  const int lr = lane & 15;
  const int kg = lane >> 4;

  // staging role: waves 0-1 -> Ahi, 2-3 -> Alo, 4-5 -> Bhi, 6-7 -> Blo
  const _Float16* gsrc;
  int lofs;        // wave's slice offset within a buffer (halves)
  size_t gstep;    // per-K-step stride in halves
  const bool awave = (wid < 4);
  if (wid < 2) {
    gsrc = ahi + ((size_t)bm * 96) * AIMG + wid * 4096;
    lofs = wid * 4096;            gstep = AIMG;
  } else if (wid < 4) {
    gsrc = alo + ((size_t)bm * 96) * AIMG + (wid - 2) * 4096;
    lofs = AIMG + (wid - 2) * 4096; gstep = AIMG;
  } else if (wid < 6) {
    gsrc = bhi + ((size_t)bn * 96) * BIMG + (wid - 4) * 2048;
    lofs = 2 * AIMG + (wid - 4) * 2048; gstep = BIMG;
  } else {
    gsrc = blo + ((size_t)bn * 96) * BIMG + (wid - 6) * 2048;
    lofs = 2 * AIMG + BIMG + (wid - 6) * 2048; gstep = BIMG;
  }
  gsrc += (size_t)lane * 8;  // per-lane 16 B (matches HW dest lane*16)

// A-waves issue 8 gload_lds per tile, B-waves 4.
#define STAGE(tile)                                                          \
  do {                                                                       \
    const _Float16* g_ = gsrc + (size_t)(tile) * gstep;                      \
    _Float16* l_ = sbuf + ((tile) % NBUF) * BUF_HALVES + lofs;               \
    _Pragma("unroll")                                                        \
    for (int q_ = 0; q_ < 4; ++q_)                                           \
      __builtin_amdgcn_global_load_lds(GLOBAL_AS(g_ + q_ * 512),             \
                                       LDS_AS(l_ + q_ * 512), 16, 0, 0);     \
    if (awave) {                                                             \
      _Pragma("unroll")                                                      \
      for (int q_ = 4; q_ < 8; ++q_)                                         \
        __builtin_amdgcn_global_load_lds(GLOBAL_AS(g_ + q_ * 512),           \
                                         LDS_AS(l_ + q_ * 512), 16, 0, 0);   \
    }                                                                        \
  } while (0)

  // frag offsets (halves): A image [kg][row][8], B image [kg][col][8]
  const int abase = kg * 2048 + (wm * 64 + lr) * 8;
  const int bbase = kg * 1024 + (wn * 64 + lr) * 8;

  f32x4 acc0[4][4];  // hi*hi (scale 256)
  f32x4 acc1[4][4];  // hi*lo + lo*hi (scale 256*2048)
#pragma unroll
  for (int i = 0; i < 4; ++i)
#pragma unroll
    for (int j = 0; j < 4; ++j) {
      acc0[i][j] = (f32x4)0.0f;
      acc1[i][j] = (f32x4)0.0f;
    }

  // 12-MFMA cluster, same accumulation order as rounds 4-5 (bit-identical)
#define CLUSTER(J, Ah, Al)                                                    \
    __builtin_amdgcn_s_setprio(1);                                            \
    _Pragma("unroll")                                                         \
    for (int i_ = 0; i_ < 4; ++i_)                                            \
      acc0[i_][J] = __builtin_amdgcn_mfma_f32_16x16x32_f16(Ah[i_], bh, acc0[i_][J], 0, 0, 0); \
    _Pragma("unroll")                                                         \
    for (int i_ = 0; i_ < 4; ++i_)                                            \
      acc1[i_][J] = __builtin_amdgcn_mfma_f32_16x16x32_f16(Ah[i_], bl, acc1[i_][J], 0, 0, 0); \
    _Pragma("unroll")                                                         \
    for (int i_ = 0; i_ < 4; ++i_)                                            \
      acc1[i_][J] = __builtin_amdgcn_mfma_f32_16x16x32_f16(Al[i_], bh, acc1[i_][J], 0, 0, 0); \
    __builtin_amdgcn_s_setprio(0);

  // One K-step. Entry invariant: CAh/CAl hold tile KT's A-frags, CB0h/CB0l
  // its j=0 B-pair (prefetched last step). vmcnt(0) drains loads issued a
  // full step ago (tiles <= KT+1 resident); barrier publishes them. During
  // the 4 clusters: roll current-tile B j=1..3 from LDS AND prefetch next
  // tile's A-frags + B0 into the N* register set. At KT=NSTEP-1 the N*
  // prefetch reads a stale buffer (values never consumed) - safe.
#define STEP(KT, CAh, CAl, CB0h, CB0l, NAh, NAl, NB0h, NB0l)                  \
  {                                                                           \
    asm volatile("s_waitcnt vmcnt(0)" ::: "memory");                          \
    __builtin_amdgcn_s_barrier();                                             \
    if ((KT) + 2 < NSTEP) STAGE((KT) + 2);                                    \
    const _Float16* cb_ = sbuf + ((KT) % NBUF) * BUF_HALVES;                  \
    const _Float16* nb_ = sbuf + (((KT) + 1) % NBUF) * BUF_HALVES;            \
    const _Float16* cBhi_ = cb_ + 2 * AIMG;                                   \
    const _Float16* cBlo_ = cb_ + 2 * AIMG + BIMG;                            \
    f16x8 bh = CB0h, bl = CB0l;                                               \
    f16x8 bh_n, bl_n;                                                         \
    bh_n = *(const f16x8*)&cBhi_[bbase + 128];                                \
    bl_n = *(const f16x8*)&cBlo_[bbase + 128];                                \
    NAh[0] = *(const f16x8*)&nb_[abase];                                      \
    NAh[1] = *(const f16x8*)&nb_[abase + 128];                                \
    CLUSTER(0, CAh, CAl)                                                      \
    bh = bh_n; bl = bl_n;                                                     \
    bh_n = *(const f16x8*)&cBhi_[bbase + 256];                                \
    bl_n = *(const f16x8*)&cBlo_[bbase + 256];                                \
    NAh[2] = *(const f16x8*)&nb_[abase + 256];                                \
    NAh[3] = *(const f16x8*)&nb_[abase + 384];                                \
    CLUSTER(1, CAh, CAl)                                                      \
    bh = bh_n; bl = bl_n;                                                     \
    bh_n = *(const f16x8*)&cBhi_[bbase + 384];                                \
    bl_n = *(const f16x8*)&cBlo_[bbase + 384];                                \
    NAl[0] = *(const f16x8*)&nb_[AIMG + abase];                               \
    NAl[1] = *(const f16x8*)&nb_[AIMG + abase + 128];                         \
    CLUSTER(2, CAh, CAl)                                                      \
    bh = bh_n; bl = bl_n;                                                     \
    NAl[2] = *(const f16x8*)&nb_[AIMG + abase + 256];                         \
    NAl[3] = *(const f16x8*)&nb_[AIMG + abase + 384];                         \
    NB0h = *(const f16x8*)&nb_[2 * AIMG + bbase];                             \
    NB0l = *(const f16x8*)&nb_[2 * AIMG + BIMG + bbase];                      \
    CLUSTER(3, CAh, CAl)                                                      \
  }

  // prologue: stage tiles 0,1; preload tile-0 frags into the X register set
  STAGE(0);
  STAGE(1);
  asm volatile("s_waitcnt vmcnt(0)" ::: "memory");
  __builtin_amdgcn_s_barrier();

  f16x8 aXh[4], aXl[4], aYh[4], aYl[4];
  f16x8 bX0h, bX0l, bY0h, bY0l;
  {
    const _Float16* b0 = sbuf;
#pragma unroll
    for (int i = 0; i < 4; ++i) {
      aXh[i] = *(const f16x8*)&b0[abase + i * 128];
      aXl[i] = *(const f16x8*)&b0[AIMG + abase + i * 128];
    }
    bX0h = *(const f16x8*)&b0[2 * AIMG + bbase];
    bX0l = *(const f16x8*)&b0[2 * AIMG + BIMG + bbase];
  }

  for (int kt = 0; kt < NSTEP; kt += 2) {
    STEP(kt,     aXh, aXl, bX0h, bX0l, aYh, aYl, bY0h, bY0l)
    STEP(kt + 1, aYh, aYl, bY0h, bY0l, aXh, aXl, bX0h, bX0l)
  }
#undef STEP
#undef CLUSTER
#undef STAGE

  // fused LIF epilogue
  const float DECAYF = 0.9512294245007140f;
  const float OMD = 1.0f - DECAYF;
  const float THR = 0.615f;

  float* outZ = out;
  float* outV = out + (size_t)M_DIM * N_DIM;
  const int colbase = bn * 128 + wn * 64;
  const int rowbase = bm * 256 + wm * 64 + kg * 4;

#pragma unroll
  for (int i = 0; i < 4; ++i) {
#pragma unroll
    for (int j = 0; j < 4; ++j) {
      const int col = colbase + j * 16 + lr;
#pragma unroll
      for (int r = 0; r < 4; ++r) {
        const int row = rowbase + i * 16 + r;
        const size_t idx = (size_t)row * N_DIM + col;
        const float it = acc0[i][j][r] * (1.0f / 256.0f) +
                         acc1[i][j][r] * (1.0f / 524288.0f);
        const float vv = vin[idx];
        const float zz = zin[idx];
        const float nv = DECAYF * vv + OMD * it - THR * zz;
        const float vs = (nv - THR) / THR;
        outZ[idx] = (vs > THR) ? 1.0f : 0.0f;
        outV[idx] = nv;
      }
    }
  }
}

// ---------------------------------------------------------------------------
// Fallback (round-1 monolithic kernel) — used only if ws_size < WS_NEEDED.
// ---------------------------------------------------------------------------
#define LDK 40
__global__ __launch_bounds__(256, 2) void lif_kernel(
    const float* __restrict__ inputs, const float* __restrict__ vin,
    const float* __restrict__ zin, const float* __restrict__ w_in,
    const float* __restrict__ w_rec, float* __restrict__ out) {
  __shared__ __align__(16) _Float16 sAhi[128 * LDK];
  __shared__ __align__(16) _Float16 sAlo[128 * LDK];
  __shared__ __align__(16) _Float16 sBhi[128 * LDK];
  __shared__ __align__(16) _Float16 sBlo[128 * LDK];

  const int tid = threadIdx.x;
  const int bn = blockIdx.x;
  const int bm = blockIdx.y;
  const int srow = tid & 127;
  const int skh = tid >> 7;
  const int lane = tid & 63;
  const int wid = tid >> 6;
  const int wm = wid & 1;
  const int wn = wid >> 1;
  const int lr = lane & 15;
  const int kg = lane >> 4;
  const int aoff = (wm * 64 + lr) * LDK + kg * 8;
  const int boff = (wn * 64 + lr) * LDK + kg * 8;

  f32x4 acc0[4][4];
  f32x4 acc1[4][4];
#pragma unroll
  for (int i = 0; i < 4; ++i)
#pragma unroll
    for (int j = 0; j < 4; ++j) {
      acc0[i][j] = (f32x4)0.0f;
      acc1[i][j] = (f32x4)0.0f;
    }

  const int rowg = bm * 128 + srow;
  const int ng = bn * 128 + srow;

  for (int kt = 0; kt < NSTEP; ++kt) {
    const int k0 = kt * BK;
    f16x8 ahi[2], alo[2];
    {
      const float* aptr = (k0 < KA)
          ? inputs + (size_t)rowg * KA + (k0 + skh * 16)
          : zin + (size_t)rowg * N_DIM + (k0 - KA + skh * 16);
#pragma unroll
      for (int q = 0; q < 4; ++q) {
        const float4 f = *(const float4*)(aptr + q * 4);
        const int vi = q >> 1, ei = (q & 1) * 4;
        SPLIT(f.x, ahi[vi], alo[vi], ei + 0);
        SPLIT(f.y, ahi[vi], alo[vi], ei + 1);
        SPLIT(f.z, ahi[vi], alo[vi], ei + 2);
        SPLIT(f.w, ahi[vi], alo[vi], ei + 3);
      }
    }
    f16x8 bhi[2], blo[2];
    {
      const bool isrec = (k0 >= KA);
      const int kbase = k0 - KA + skh * 16;
      const float* bptr = isrec
          ? w_rec + (size_t)kbase * N_DIM + ng
          : w_in + (size_t)(k0 + skh * 16) * N_DIM + ng;
#pragma unroll
      for (int kk = 0; kk < 16; ++kk) {
        float x = bptr[(size_t)kk * N_DIM];
        if (isrec && (kbase + kk == ng)) x = 0.0f;
        x *= 256.0f;
        SPLIT(x, bhi[kk >> 3], blo[kk >> 3], kk & 7);
      }
    }

    __syncthreads();
    {
      _Float16* pA = &sAhi[srow * LDK + skh * 16];
      *(f16x8*)(pA + 0) = ahi[0];
      *(f16x8*)(pA + 8) = ahi[1];
      _Float16* pAl = &sAlo[srow * LDK + skh * 16];
      *(f16x8*)(pAl + 0) = alo[0];
      *(f16x8*)(pAl + 8) = alo[1];
      _Float16* pB = &sBhi[srow * LDK + skh * 16];
      *(f16x8*)(pB + 0) = bhi[0];
      *(f16x8*)(pB + 8) = bhi[1];
      _Float16* pBl = &sBlo[srow * LDK + skh * 16];
      *(f16x8*)(pBl + 0) = blo[0];
      *(f16x8*)(pBl + 8) = blo[1];
    }
    __syncthreads();

    f16x8 ah[4], al[4];
#pragma unroll
    for (int i = 0; i < 4; ++i) {
      ah[i] = *(const f16x8*)&sAhi[aoff + i * 16 * LDK];
      al[i] = *(const f16x8*)&sAlo[aoff + i * 16 * LDK];
    }
#pragma unroll
    for (int j = 0; j < 4; ++j) {
      const f16x8 bh = *(const f16x8*)&sBhi[boff + j * 16 * LDK];
      const f16x8 bl = *(const f16x8*)&sBlo[boff + j * 16 * LDK];
#pragma unroll
      for (int i = 0; i < 4; ++i)
        acc0[i][j] = __builtin_amdgcn_mfma_f32_16x16x32_f16(ah[i], bh, acc0[i][j], 0, 0, 0);
#pragma unroll
      for (int i = 0; i < 4; ++i)
        acc1[i][j] = __builtin_amdgcn_mfma_f32_16x16x32_f16(ah[i], bl, acc1[i][j], 0, 0, 0);
#pragma unroll
      for (int i = 0; i < 4; ++i)
        acc1[i][j] = __builtin_amdgcn_mfma_f32_16x16x32_f16(al[i], bh, acc1[i][j], 0, 0, 0);
    }
  }

  const float DECAYF = 0.9512294245007140f;
  const float OMD = 1.0f - DECAYF;
  const float THR = 0.615f;
  float* outZ = out;
  float* outV = out + (size_t)M_DIM * N_DIM;
  const int colbase = bn * 128 + wn * 64;
  const int rowbase = bm * 128 + wm * 64 + kg * 4;
#pragma unroll
  for (int i = 0; i < 4; ++i) {
#pragma unroll
    for (int j = 0; j < 4; ++j) {
      const int col = colbase + j * 16 + lr;
#pragma unroll
      for (int r = 0; r < 4; ++r) {
        const int row = rowbase + i * 16 + r;
        const size_t idx = (size_t)row * N_DIM + col;
        const float it = acc0[i][j][r] * (1.0f / 256.0f) +
                         acc1[i][j][r] * (1.0f / 524288.0f);
        const float vv = vin[idx];
        const float zz = zin[idx];
        const float nv = DECAYF * vv + OMD * it - THR * zz;
        const float vs = (nv - THR) / THR;
        outZ[idx] = (vs > THR) ? 1.0f : 0.0f;
        outV[idx] = nv;
      }
    }
  }
}

extern "C" void kernel_launch(void* const* d_in, const int* in_sizes, int n_in,
                              void* d_out, int out_size, void* d_ws, size_t ws_size,
                              hipStream_t stream) {
  const float* inputs = (const float*)d_in[0];
  const float* v      = (const float*)d_in[1];
  const float* z      = (const float*)d_in[2];
  const float* w_in   = (const float*)d_in[3];
  const float* w_rec  = (const float*)d_in[4];
  float* out = (float*)d_out;

  if (ws_size >= WS_NEEDED) {
    _Float16* ahi = (_Float16*)d_ws;
    _Float16* alo = (_Float16*)((char*)d_ws + SZ_AH);
    _Float16* bhi = (_Float16*)((char*)d_ws + 2 * SZ_AH);
    _Float16* blo = (_Float16*)((char*)d_ws + 2 * SZ_AH + SZ_BH);

    // allow 144 KB dynamic LDS (gfx950 has 160 KB/CU); idempotent, capture-safe
    static_assert(NBUF * BUF_HALVES * sizeof(_Float16) == 147456, "LDS size");
    (void)hipFuncSetAttribute((const void*)lif_gemm,
                              hipFuncAttributeMaxDynamicSharedMemorySize, LDS_BYTES);

    hipLaunchKernelGGL(prep_ab, dim3(96, 16), dim3(256), 0, stream,
                       inputs, z, w_in, w_rec, ahi, alo, bhi, blo);
    hipLaunchKernelGGL(lif_gemm, dim3(16, 16), dim3(512), LDS_BYTES, stream,
                       ahi, alo, bhi, blo, v, z, out);
  } else {
    hipLaunchKernelGGL(lif_kernel, dim3(16, 32), dim3(256), 0, stream,
                       inputs, v, z, w_in, w_rec, out);
  }
}

// Round 3
// 303.529 us; speedup vs baseline: 1.0083x; 1.0083x over previous
//
#include <hip/hip_runtime.h>

// LightLIF fused step on MI355X (gfx950) — round 7.
//
//   A = [inputs | z]            : [4096, 3072] fp32   (M x K)
//   Bm = [w_in ; w_rec*(1-eye)] : [3072, 2048] fp32   (K x N), B pre-scaled by 256
//   i_t = A @ Bm    (fp32-accurate via f16 Markidis split, 3 MFMA passes)
//   new_v = DECAY*v + (1-DECAY)*i_t - 0.615*z ; spike vs THR
//   d_out = [new_z (M*N) | new_v (M*N)]
//
// Round-7 theory: MFMA blocks its issuing wave, so intra-wave ds_read/MFMA
// overlap is impossible; with 144 KB LDS we had 1 block/CU and both waves on
// each SIMD barrier-locked into the same phase -> LDS and MFMA phases ran
// SERIALLY (wall 4175 cy/step ~ 1862 MFMA + 1730 LDS). Fix: 128x128 tile,
// 4 waves/block, 64 KB LDS double-buffer -> 2 independent blocks/CU. Their
// un-synchronized barriers anti-phase, so one block's LDS burst runs under
// the other's MFMA burst (the m114 mechanism). Numerics bit-identical.

#define M_DIM 4096
#define N_DIM 2048
#define K_DIM 3072
#define KA    1024
#define BK    32
#define NSTEP (K_DIM / BK)          // 96
#define AIMG  4096                  // halves: 4 k-octets x 128 rows x 8
#define BIMG  4096                  // halves: 4 k-octets x 128 cols x 8
#define BUF_HALVES (AIMG + AIMG + BIMG + BIMG)  // 16384 halves = 32 KB
#define NBUF 2
#define LDS_BYTES (NBUF * BUF_HALVES * 2)       // 65536 B = 64 KB

#define SZ_AH ((size_t)32 * 96 * AIMG * 2)  // 25,165,824 B (one of hi/lo)
#define SZ_BH ((size_t)16 * 96 * BIMG * 2)  // 12,582,912 B
#define WS_NEEDED (2 * SZ_AH + 2 * SZ_BH)   // 75,497,472 B

typedef _Float16 f16x8 __attribute__((ext_vector_type(8)));
typedef float    f32x4 __attribute__((ext_vector_type(4)));

#define GLOBAL_AS(p) ((const __attribute__((address_space(1))) void*)(p))
#define LDS_AS(p)    ((__attribute__((address_space(3))) void*)(p))

// hi/lo split with lo pre-scaled by 2048 (RNE conversions)
#define SPLIT(x, dsthi, dstlo, idx)                                  \
  {                                                                  \
    _Float16 _h = (_Float16)(x);                                     \
    float    _r = ((x) - (float)_h) * 2048.0f;                       \
    dsthi[idx] = _h;                                                 \
    dstlo[idx] = (_Float16)_r;                                       \
  }

// ---------------------------------------------------------------------------
// prep_ab: merged A-split and B-split. grid (96 kt, 32 bg), block 256.
// A part: all 256 threads handle bm=bg (128 rows, 2 rows/thread).
// B part: threads 0..127 handle bn=bg, only for bg<16.
// A image layout [kg 4][row 128][8]; B image [kg 4][col 128][8].
// ---------------------------------------------------------------------------
__global__ void prep_ab(const float* __restrict__ inputs,
                        const float* __restrict__ z,
                        const float* __restrict__ w_in,
                        const float* __restrict__ w_rec,
                        _Float16* __restrict__ ahi, _Float16* __restrict__ alo,
                        _Float16* __restrict__ bhi, _Float16* __restrict__ blo) {
  const int kt = blockIdx.x, bg = blockIdx.y;
  const int t = threadIdx.x;

  // ---- A part
  {
    const int s = t & 3;       // k-octet 0..3
    const int rr = t >> 2;     // 0..63
    const int k0 = kt * BK + s * 8;
    const size_t img = ((size_t)bg * 96 + kt) * AIMG;
#pragma unroll
    for (int p = 0; p < 2; ++p) {
      const int row = p * 64 + rr;
      const int rg = bg * 128 + row;
      const float* src = (kt < 32) ? inputs + (size_t)rg * KA + k0
                                   : z + (size_t)rg * N_DIM + (k0 - KA);
      const float4 f0 = *(const float4*)(src);
      const float4 f1 = *(const float4*)(src + 4);
      f16x8 hi, lo;
      SPLIT(f0.x, hi, lo, 0);
      SPLIT(f0.y, hi, lo, 1);
      SPLIT(f0.z, hi, lo, 2);
      SPLIT(f0.w, hi, lo, 3);
      SPLIT(f1.x, hi, lo, 4);
      SPLIT(f1.y, hi, lo, 5);
      SPLIT(f1.z, hi, lo, 6);
      SPLIT(f1.w, hi, lo, 7);
      const size_t o = img + (size_t)s * 1024 + (size_t)row * 8;
      *(f16x8*)&ahi[o] = hi;
      *(f16x8*)&alo[o] = lo;
    }
  }

  // ---- B part (only 16 bn panels exist)
  if (bg < 16 && t < 128) {
    const int c = t;                // 0..127
    const int ng = bg * 128 + c;
    const int k0 = kt * BK;
    f16x8 hi[4], lo[4];
#pragma unroll
    for (int kk = 0; kk < BK; ++kk) {
      const int k = k0 + kk;
      float x = (k < KA) ? w_in[(size_t)k * N_DIM + ng]
                         : w_rec[(size_t)(k - KA) * N_DIM + ng];
      if (k >= KA && (k - KA) == ng) x = 0.0f;   // zero diagonal of w_rec
      x *= 256.0f;                               // keep hi-parts normal in f16
      SPLIT(x, hi[kk >> 3], lo[kk >> 3], kk & 7);
    }
    const size_t img = ((size_t)bg * 96 + kt) * BIMG + (size_t)c * 8;
#pragma unroll
    for (int q = 0; q < 4; ++q) {
      *(f16x8*)&bhi[img + (size_t)q * 1024] = hi[q];
      *(f16x8*)&blo[img + (size_t)q * 1024] = lo[q];
    }
  }
}

// ---------------------------------------------------------------------------
// GEMM + fused LIF epilogue. grid (16 bn, 32 bm) [bn on x -> each XCD owns
// 2 bn panels, B L2-resident]. Block 256 = 4 waves (2m x 2n of 64x64).
// 64 KB LDS double-buffer -> 2 blocks/CU; independent block barriers give
// inter-block LDS/MFMA phase overlap. Each wave stages exactly one 8 KB
// image (8 x 16B global_load_lds) -> vmcnt(0) per step is exact.
// ---------------------------------------------------------------------------
__global__ __launch_bounds__(256, 2) void lif_gemm(
    const _Float16* __restrict__ ahi, const _Float16* __restrict__ alo,
    const _Float16* __restrict__ bhi, const _Float16* __restrict__ blo,
    const float* __restrict__ vin, const float* __restrict__ zin,
    float* __restrict__ out) {
  extern __shared__ __align__(16) _Float16 sbuf[];  // NBUF * BUF_HALVES = 64 KB

  const int tid = threadIdx.x;
  const int bn = blockIdx.x;   // 16; consecutive ids vary bn -> B XCD-local
  const int bm = blockIdx.y;   // 32
  const int lane = tid & 63;
  const int wid = tid >> 6;       // 0..3
  const int wm = wid & 1;         // m-half (2 x 64)
  const int wn = wid >> 1;        // n-half (2 x 64)
  const int lr = lane & 15;
  const int kg = lane >> 4;

  // staging role: wave 0 -> Ahi, 1 -> Alo, 2 -> Bhi, 3 -> Blo (8 KB each)
  const _Float16* gsrc;
  int lofs;        // wave's image offset within a buffer (halves)
  if (wid == 0)      { gsrc = ahi + (size_t)bm * 96 * AIMG; lofs = 0; }
  else if (wid == 1) { gsrc = alo + (size_t)bm * 96 * AIMG; lofs = AIMG; }
  else if (wid == 2) { gsrc = bhi + (size_t)bn * 96 * BIMG; lofs = 2 * AIMG; }
  else               { gsrc = blo + (size_t)bn * 96 * BIMG; lofs = 2 * AIMG + BIMG; }
  gsrc += (size_t)lane * 8;  // per-lane 16 B (matches HW dest lane*16)

// every wave: 8 x 16B global_load_lds per tile (one 4096-half image)
#define STAGE(tile)                                                          \
  do {                                                                       \
    const _Float16* g_ = gsrc + (size_t)(tile) * 4096;                       \
    _Float16* l_ = sbuf + ((tile) & 1) * BUF_HALVES + lofs;                  \
    _Pragma("unroll")                                                        \
    for (int q_ = 0; q_ < 8; ++q_)                                           \
      __builtin_amdgcn_global_load_lds(GLOBAL_AS(g_ + q_ * 512),             \
                                       LDS_AS(l_ + q_ * 512), 16, 0, 0);     \
  } while (0)

  // frag offsets (halves): A image [kg][row][8], B image [kg][col][8]
  const int abase = kg * 1024 + (wm * 64 + lr) * 8;
  const int bbase = kg * 1024 + (wn * 64 + lr) * 8;

  f32x4 acc0[4][4];  // hi*hi (scale 256)
  f32x4 acc1[4][4];  // hi*lo + lo*hi (scale 256*2048)
#pragma unroll
  for (int i = 0; i < 4; ++i)
#pragma unroll
    for (int j = 0; j < 4; ++j) {
      acc0[i][j] = (f32x4)0.0f;
      acc1[i][j] = (f32x4)0.0f;
    }

  // 12-MFMA cluster, same accumulation order as rounds 4-6 (bit-identical)
#define CLUSTER(J)                                                            \
    __builtin_amdgcn_s_setprio(1);                                            \
    _Pragma("unroll")                                                         \
    for (int i_ = 0; i_ < 4; ++i_)                                            \
      acc0[i_][J] = __builtin_amdgcn_mfma_f32_16x16x32_f16(ah[i_], bh, acc0[i_][J], 0, 0, 0); \
    _Pragma("unroll")                                                         \
    for (int i_ = 0; i_ < 4; ++i_)                                            \
      acc1[i_][J] = __builtin_amdgcn_mfma_f32_16x16x32_f16(ah[i_], bl, acc1[i_][J], 0, 0, 0); \
    _Pragma("unroll")                                                         \
    for (int i_ = 0; i_ < 4; ++i_)                                            \
      acc1[i_][J] = __builtin_amdgcn_mfma_f32_16x16x32_f16(al[i_], bh, acc1[i_][J], 0, 0, 0); \
    __builtin_amdgcn_s_setprio(0);

  // prologue: stage tile 0
  STAGE(0);

  for (int kt = 0; kt < NSTEP; ++kt) {
    // distance-1: STAGE(kt) was issued one full compute phase ago; nothing
    // newer is in flight for this wave -> vmcnt(0) is the exact counted wait.
    asm volatile("s_waitcnt vmcnt(0)" ::: "memory");
    __builtin_amdgcn_s_barrier();
    if (kt + 1 < NSTEP) STAGE(kt + 1);

    const _Float16* base = sbuf + (kt & 1) * BUF_HALVES;
    const _Float16* pBhi = base + 2 * AIMG;
    const _Float16* pBlo = base + 2 * AIMG + BIMG;

    f16x8 ah[4], al[4];
#pragma unroll
    for (int i = 0; i < 4; ++i) {
      ah[i] = *(const f16x8*)&base[abase + i * 128];
      al[i] = *(const f16x8*)&base[AIMG + abase + i * 128];
    }
    f16x8 bh = *(const f16x8*)&pBhi[bbase];
    f16x8 bl = *(const f16x8*)&pBlo[bbase];
#pragma unroll
    for (int j = 0; j < 4; ++j) {
      f16x8 bh_n, bl_n;
      if (j < 3) {  // roll next B-pair under this cluster's MFMAs
        bh_n = *(const f16x8*)&pBhi[bbase + (j + 1) * 128];
        bl_n = *(const f16x8*)&pBlo[bbase + (j + 1) * 128];
      }
      CLUSTER(j)
      if (j < 3) { bh = bh_n; bl = bl_n; }
    }
  }
#undef CLUSTER
#undef STAGE

  // fused LIF epilogue
  const float DECAYF = 0.9512294245007140f;
  const float OMD = 1.0f - DECAYF;
  const float THR = 0.615f;

  float* outZ = out;
  float* outV = out + (size_t)M_DIM * N_DIM;
  const int colbase = bn * 128 + wn * 64;
  const int rowbase = bm * 128 + wm * 64 + kg * 4;

#pragma unroll
  for (int i = 0; i < 4; ++i) {
#pragma unroll
    for (int j = 0; j < 4; ++j) {
      const int col = colbase + j * 16 + lr;
#pragma unroll
      for (int r = 0; r < 4; ++r) {
        const int row = rowbase + i * 16 + r;
        const size_t idx = (size_t)row * N_DIM + col;
        const float it = acc0[i][j][r] * (1.0f / 256.0f) +
                         acc1[i][j][r] * (1.0f / 524288.0f);
        const float vv = vin[idx];
        const float zz = zin[idx];
        const float nv = DECAYF * vv + OMD * it - THR * zz;
        const float vs = (nv - THR) / THR;
        outZ[idx] = (vs > THR) ? 1.0f : 0.0f;
        outV[idx] = nv;
      }
    }
  }
}

// ---------------------------------------------------------------------------
// Fallback (round-1 monolithic kernel) — used only if ws_size < WS_NEEDED.
// ---------------------------------------------------------------------------
#define LDK 40
__global__ __launch_bounds__(256, 2) void lif_kernel(
    const float* __restrict__ inputs, const float* __restrict__ vin,
    const float* __restrict__ zin, const float* __restrict__ w_in,
    const float* __restrict__ w_rec, float* __restrict__ out) {
  __shared__ __align__(16) _Float16 sAhi[128 * LDK];
  __shared__ __align__(16) _Float16 sAlo[128 * LDK];
  __shared__ __align__(16) _Float16 sBhi[128 * LDK];
  __shared__ __align__(16) _Float16 sBlo[128 * LDK];

  const int tid = threadIdx.x;
  const int bn = blockIdx.x;
  const int bm = blockIdx.y;
  const int srow = tid & 127;
  const int skh = tid >> 7;
  const int lane = tid & 63;
  const int wid = tid >> 6;
  const int wm = wid & 1;
  const int wn = wid >> 1;
  const int lr = lane & 15;
  const int kg = lane >> 4;
  const int aoff = (wm * 64 + lr) * LDK + kg * 8;
  const int boff = (wn * 64 + lr) * LDK + kg * 8;

  f32x4 acc0[4][4];
  f32x4 acc1[4][4];
#pragma unroll
  for (int i = 0; i < 4; ++i)
#pragma unroll
    for (int j = 0; j < 4; ++j) {
      acc0[i][j] = (f32x4)0.0f;
      acc1[i][j] = (f32x4)0.0f;
    }

  const int rowg = bm * 128 + srow;
  const int ng = bn * 128 + srow;

  for (int kt = 0; kt < NSTEP; ++kt) {
    const int k0 = kt * BK;
    f16x8 ahi[2], alo[2];
    {
      const float* aptr = (k0 < KA)
          ? inputs + (size_t)rowg * KA + (k0 + skh * 16)
          : zin + (size_t)rowg * N_DIM + (k0 - KA + skh * 16);
#pragma unroll
      for (int q = 0; q < 4; ++q) {
        const float4 f = *(const float4*)(aptr + q * 4);
        const int vi = q >> 1, ei = (q & 1) * 4;
        SPLIT(f.x, ahi[vi], alo[vi], ei + 0);
        SPLIT(f.y, ahi[vi], alo[vi], ei + 1);
        SPLIT(f.z, ahi[vi], alo[vi], ei + 2);
        SPLIT(f.w, ahi[vi], alo[vi], ei + 3);
      }
    }
    f16x8 bhi[2], blo[2];
    {
      const bool isrec = (k0 >= KA);
      const int kbase = k0 - KA + skh * 16;
      const float* bptr = isrec
          ? w_rec + (size_t)kbase * N_DIM + ng
          : w_in + (size_t)(k0 + skh * 16) * N_DIM + ng;
#pragma unroll
      for (int kk = 0; kk < 16; ++kk) {
        float x = bptr[(size_t)kk * N_DIM];
        if (isrec && (kbase + kk == ng)) x = 0.0f;
        x *= 256.0f;
        SPLIT(x, bhi[kk >> 3], blo[kk >> 3], kk & 7);
      }
    }

    __syncthreads();
    {
      _Float16* pA = &sAhi[srow * LDK + skh * 16];
      *(f16x8*)(pA + 0) = ahi[0];
      *(f16x8*)(pA + 8) = ahi[1];
      _Float16* pAl = &sAlo[srow * LDK + skh * 16];
      *(f16x8*)(pAl + 0) = alo[0];
      *(f16x8*)(pAl + 8) = alo[1];
      _Float16* pB = &sBhi[srow * LDK + skh * 16];
      *(f16x8*)(pB + 0) = bhi[0];
      *(f16x8*)(pB + 8) = bhi[1];
      _Float16* pBl = &sBlo[srow * LDK + skh * 16];
      *(f16x8*)(pBl + 0) = blo[0];
      *(f16x8*)(pBl + 8) = blo[1];
    }
    __syncthreads();

    f16x8 ah[4], al[4];
#pragma unroll
    for (int i = 0; i < 4; ++i) {
      ah[i] = *(const f16x8*)&sAhi[aoff + i * 16 * LDK];
      al[i] = *(const f16x8*)&sAlo[aoff + i * 16 * LDK];
    }
#pragma unroll
    for (int j = 0; j < 4; ++j) {
      const f16x8 bh = *(const f16x8*)&sBhi[boff + j * 16 * LDK];
      const f16x8 bl = *(const f16x8*)&sBlo[boff + j * 16 * LDK];
#pragma unroll
      for (int i = 0; i < 4; ++i)
        acc0[i][j] = __builtin_amdgcn_mfma_f32_16x16x32_f16(ah[i], bh, acc0[i][j], 0, 0, 0);
#pragma unroll
      for (int i = 0; i < 4; ++i)
        acc1[i][j] = __builtin_amdgcn_mfma_f32_16x16x32_f16(ah[i], bl, acc1[i][j], 0, 0, 0);
#pragma unroll
      for (int i = 0; i < 4; ++i)
        acc1[i][j] = __builtin_amdgcn_mfma_f32_16x16x32_f16(al[i], bh, acc1[i][j], 0, 0, 0);
    }
  }

  const float DECAYF = 0.9512294245007140f;
  const float OMD = 1.0f - DECAYF;
  const float THR = 0.615f;
  float* outZ = out;
  float* outV = out + (size_t)M_DIM * N_DIM;
  const int colbase = bn * 128 + wn * 64;
  const int rowbase = bm * 128 + wm * 64 + kg * 4;
#pragma unroll
  for (int i = 0; i < 4; ++i) {
#pragma unroll
    for (int j = 0; j < 4; ++j) {
      const int col = colbase + j * 16 + lr;
#pragma unroll
      for (int r = 0; r < 4; ++r) {
        const int row = rowbase + i * 16 + r;
        const size_t idx = (size_t)row * N_DIM + col;
        const float it = acc0[i][j][r] * (1.0f / 256.0f) +
                         acc1[i][j][r] * (1.0f / 524288.0f);
        const float vv = vin[idx];
        const float zz = zin[idx];
        const float nv = DECAYF * vv + OMD * it - THR * zz;
        const float vs = (nv - THR) / THR;
        outZ[idx] = (vs > THR) ? 1.0f : 0.0f;
        outV[idx] = nv;
      }
    }
  }
}

extern "C" void kernel_launch(void* const* d_in, const int* in_sizes, int n_in,
                              void* d_out, int out_size, void* d_ws, size_t ws_size,
                              hipStream_t stream) {
  const float* inputs = (const float*)d_in[0];
  const float* v      = (const float*)d_in[1];
  const float* z      = (const float*)d_in[2];
  const float* w_in   = (const float*)d_in[3];
  const float* w_rec  = (const float*)d_in[4];
  float* out = (float*)d_out;

  if (ws_size >= WS_NEEDED) {
    _Float16* ahi = (_Float16*)d_ws;
    _Float16* alo = (_Float16*)((char*)d_ws + SZ_AH);
    _Float16* bhi = (_Float16*)((char*)d_ws + 2 * SZ_AH);
    _Float16* blo = (_Float16*)((char*)d_ws + 2 * SZ_AH + SZ_BH);

    // allow 64 KB dynamic LDS; idempotent, capture-safe
    static_assert(NBUF * BUF_HALVES * sizeof(_Float16) == 65536, "LDS size");
    (void)hipFuncSetAttribute((const void*)lif_gemm,
                              hipFuncAttributeMaxDynamicSharedMemorySize, LDS_BYTES);

    hipLaunchKernelGGL(prep_ab, dim3(96, 32), dim3(256), 0, stream,
                       inputs, z, w_in, w_rec, ahi, alo, bhi, blo);
    hipLaunchKernelGGL(lif_gemm, dim3(16, 32), dim3(256), LDS_BYTES, stream,
                       ahi, alo, bhi, blo, v, z, out);
  } else {
    hipLaunchKernelGGL(lif_kernel, dim3(16, 32), dim3(256), 0, stream,
                       inputs, v, z, w_in, w_rec, out);
  }
}

// Round 4
// 301.940 us; speedup vs baseline: 1.0136x; 1.0053x over previous
//
#include <hip/hip_runtime.h>

// LightLIF fused step on MI355X (gfx950) — round 8.
//
//   A = [inputs | z]            : [4096, 3072] fp32   (M x K)
//   Bm = [w_in ; w_rec*(1-eye)] : [3072, 2048] fp32   (K x N), B pre-scaled by 256
//   i_t = A @ Bm    (fp32-accurate via f16 Markidis split, 3 MFMA passes)
//   new_v = DECAY*v + (1-DECAY)*i_t - 0.615*z ; spike vs THR
//   d_out = [new_z (M*N) | new_v (M*N)]
//
// Round-8: rounds 5-7 proved the one-barrier-per-step structure phase-locks
// LDS and MFMA bursts into a serial sum (~4000 cy/step) regardless of macro
// schedule. This round is a faithful port of the proven m201 8-phase cadence:
// per K-step, THREE 16-MFMA phases (split by Markidis pass, preserving each
// accumulator's op order -> bit-identical), each phase = {ds_reads for this
// phase; (staging in P1); s_barrier; lgkmcnt(0); setprio(1); 16 MFMA;
// setprio(0); s_barrier}, sched_barrier(0) pins. 3-deep 144 KB ring,
// distance-2 staging, counted vmcnt(8/4) only at the step boundary.

#define M_DIM 4096
#define N_DIM 2048
#define K_DIM 3072
#define KA    1024
#define BK    32
#define NSTEP (K_DIM / BK)          // 96
#define AIMG  8192                  // halves: 4 k-octets x 256 rows x 8
#define BIMG  4096                  // halves: 4 k-octets x 128 cols x 8
#define BUF_HALVES (2 * AIMG + 2 * BIMG)  // 24576 halves = 48 KB per buffer
#define NBUF 3
#define LDS_BYTES (NBUF * BUF_HALVES * 2) // 147456 B = 144 KB

#define SZ_AH ((size_t)16 * 96 * AIMG * 2)  // 25,165,824 B (one of hi/lo)
#define SZ_BH ((size_t)16 * 96 * BIMG * 2)  // 12,582,912 B
#define WS_NEEDED (2 * SZ_AH + 2 * SZ_BH)   // 75,497,472 B

typedef _Float16 f16x8 __attribute__((ext_vector_type(8)));
typedef float    f32x4 __attribute__((ext_vector_type(4)));

#define GLOBAL_AS(p) ((const __attribute__((address_space(1))) void*)(p))
#define LDS_AS(p)    ((__attribute__((address_space(3))) void*)(p))

// hi/lo split with lo pre-scaled by 2048 (RNE conversions)
#define SPLIT(x, dsthi, dstlo, idx)                                  \
  {                                                                  \
    _Float16 _h = (_Float16)(x);                                     \
    float    _r = ((x) - (float)_h) * 2048.0f;                       \
    dsthi[idx] = _h;                                                 \
    dstlo[idx] = (_Float16)_r;                                       \
  }

// ---------------------------------------------------------------------------
// prep_ab: merged A-split and B-split. grid (96 kt, 16 bg), block 256.
// A: all 256 threads, bm=bg, 256 rows (4 rows/thread), layout [kg][row 256][8].
// B: threads 0..127, bn=bg, layout [kg][col 128][8].
// ---------------------------------------------------------------------------
__global__ void prep_ab(const float* __restrict__ inputs,
                        const float* __restrict__ z,
                        const float* __restrict__ w_in,
                        const float* __restrict__ w_rec,
                        _Float16* __restrict__ ahi, _Float16* __restrict__ alo,
                        _Float16* __restrict__ bhi, _Float16* __restrict__ blo) {
  const int kt = blockIdx.x, bg = blockIdx.y;
  const int t = threadIdx.x;

  // ---- A part
  {
    const int s = t & 3;       // k-octet 0..3
    const int rr = t >> 2;     // 0..63
    const int k0 = kt * BK + s * 8;
    const size_t img = ((size_t)bg * 96 + kt) * AIMG;
#pragma unroll
    for (int p = 0; p < 4; ++p) {
      const int row = p * 64 + rr;
      const int rg = bg * 256 + row;
      const float* src = (kt < 32) ? inputs + (size_t)rg * KA + k0
                                   : z + (size_t)rg * N_DIM + (k0 - KA);
      const float4 f0 = *(const float4*)(src);
      const float4 f1 = *(const float4*)(src + 4);
      f16x8 hi, lo;
      SPLIT(f0.x, hi, lo, 0);
      SPLIT(f0.y, hi, lo, 1);
      SPLIT(f0.z, hi, lo, 2);
      SPLIT(f0.w, hi, lo, 3);
      SPLIT(f1.x, hi, lo, 4);
      SPLIT(f1.y, hi, lo, 5);
      SPLIT(f1.z, hi, lo, 6);
      SPLIT(f1.w, hi, lo, 7);
      const size_t o = img + (size_t)s * 2048 + (size_t)row * 8;
      *(f16x8*)&ahi[o] = hi;
      *(f16x8*)&alo[o] = lo;
    }
  }

  // ---- B part
  if (t < 128) {
    const int c = t;                // 0..127
    const int ng = bg * 128 + c;
    const int k0 = kt * BK;
    f16x8 hi[4], lo[4];
#pragma unroll
    for (int kk = 0; kk < BK; ++kk) {
      const int k = k0 + kk;
      float x = (k < KA) ? w_in[(size_t)k * N_DIM + ng]
                         : w_rec[(size_t)(k - KA) * N_DIM + ng];
      if (k >= KA && (k - KA) == ng) x = 0.0f;   // zero diagonal of w_rec
      x *= 256.0f;                               // keep hi-parts normal in f16
      SPLIT(x, hi[kk >> 3], lo[kk >> 3], kk & 7);
    }
    const size_t img = ((size_t)bg * 96 + kt) * BIMG + (size_t)c * 8;
#pragma unroll
    for (int q = 0; q < 4; ++q) {
      *(f16x8*)&bhi[img + (size_t)q * 1024] = hi[q];
      *(f16x8*)&blo[img + (size_t)q * 1024] = lo[q];
    }
  }
}

// ---------------------------------------------------------------------------
// GEMM + fused LIF epilogue. grid (16 bm, 16 bn), block 512 (8 waves, 4m x 2n
// of 64x64). 144 KB 3-ring LDS, distance-2 staging, counted vmcnt(8/4) at
// step boundary only. Per step: 3 phases of 16 MFMA (split by Markidis pass),
// m201 cadence: reads; bar; lgkmcnt(0); setprio; MFMA; setprio; bar.
// ---------------------------------------------------------------------------
__global__ __launch_bounds__(512, 2) void lif_gemm(
    const _Float16* __restrict__ ahi, const _Float16* __restrict__ alo,
    const _Float16* __restrict__ bhi, const _Float16* __restrict__ blo,
    const float* __restrict__ vin, const float* __restrict__ zin,
    float* __restrict__ out) {
  extern __shared__ __align__(16) _Float16 sbuf[];  // NBUF * BUF_HALVES = 144 KB

  const int tid = threadIdx.x;
  const int bm = blockIdx.x;   // same-bm blocks share XCD -> A L2-local
  const int bn = blockIdx.y;
  const int lane = tid & 63;
  const int wid = tid >> 6;       // 0..7
  const int wm = wid & 3;         // m-quadrant (4 x 64)
  const int wn = wid >> 2;        // n-half (2 x 64)
  const int lr = lane & 15;
  const int kg = lane >> 4;

  // staging role: waves 0-1 -> Ahi, 2-3 -> Alo, 4-5 -> Bhi, 6-7 -> Blo
  const _Float16* gsrc;
  int lofs;        // wave's slice offset within a buffer (halves)
  size_t gstep;    // per-K-step stride in halves
  const bool awave = (wid < 4);
  if (wid < 2) {
    gsrc = ahi + ((size_t)bm * 96) * AIMG + wid * 4096;
    lofs = wid * 4096;            gstep = AIMG;
  } else if (wid < 4) {
    gsrc = alo + ((size_t)bm * 96) * AIMG + (wid - 2) * 4096;
    lofs = AIMG + (wid - 2) * 4096; gstep = AIMG;
  } else if (wid < 6) {
    gsrc = bhi + ((size_t)bn * 96) * BIMG + (wid - 4) * 2048;
    lofs = 2 * AIMG + (wid - 4) * 2048; gstep = BIMG;
  } else {
    gsrc = blo + ((size_t)bn * 96) * BIMG + (wid - 6) * 2048;
    lofs = 2 * AIMG + BIMG + (wid - 6) * 2048; gstep = BIMG;
  }
  gsrc += (size_t)lane * 8;  // per-lane 16 B (matches HW dest lane*16)

// A-waves issue 8 gload_lds per tile, B-waves 4.
#define STAGE(tile)                                                          \
  do {                                                                       \
    const _Float16* g_ = gsrc + (size_t)(tile) * gstep;                      \
    _Float16* l_ = sbuf + ((tile) % NBUF) * BUF_HALVES + lofs;               \
    _Pragma("unroll")                                                        \
    for (int q_ = 0; q_ < 4; ++q_)                                           \
      __builtin_amdgcn_global_load_lds(GLOBAL_AS(g_ + q_ * 512),             \
                                       LDS_AS(l_ + q_ * 512), 16, 0, 0);     \
    if (awave) {                                                             \
      _Pragma("unroll")                                                      \
      for (int q_ = 4; q_ < 8; ++q_)                                         \
        __builtin_amdgcn_global_load_lds(GLOBAL_AS(g_ + q_ * 512),           \
                                         LDS_AS(l_ + q_ * 512), 16, 0, 0);   \
    }                                                                        \
  } while (0)

  // frag offsets (halves): A image [kg][row][8], B image [kg][col][8]
  const int abase = kg * 2048 + (wm * 64 + lr) * 8;
  const int bbase = kg * 1024 + (wn * 64 + lr) * 8;

  f32x4 acc0[4][4];  // hi*hi (scale 256)
  f32x4 acc1[4][4];  // hi*lo + lo*hi (scale 256*2048)
#pragma unroll
  for (int i = 0; i < 4; ++i)
#pragma unroll
    for (int j = 0; j < 4; ++j) {
      acc0[i][j] = (f32x4)0.0f;
      acc1[i][j] = (f32x4)0.0f;
    }

  // prologue: stage tiles 0,1 (distance-2 ring fill)
  STAGE(0);
  STAGE(1);

  for (int kt = 0; kt < NSTEP; ++kt) {
    // ---- step boundary: counted wait. Outstanding here = stage(kt) [oldest]
    // + stage(kt+1) [issued during step kt-1]. Drain stage(kt) only.
    if (kt + 1 < NSTEP) {
      if (awave) asm volatile("s_waitcnt vmcnt(8)" ::: "memory");
      else       asm volatile("s_waitcnt vmcnt(4)" ::: "memory");
    } else {
      asm volatile("s_waitcnt vmcnt(0)" ::: "memory");
    }
    __builtin_amdgcn_s_barrier();   // buf kt%3 published; buf (kt+2)%3 dead
    __builtin_amdgcn_sched_barrier(0);

    const _Float16* base = sbuf + (kt % NBUF) * BUF_HALVES;
    const _Float16* pAlo = base + AIMG;
    const _Float16* pBhi = base + 2 * AIMG;
    const _Float16* pBlo = base + 2 * AIMG + BIMG;

    // ---- P1: reads {ah x4, bh x4}; issue staging; 16 MFMA acc0 += ah*bh
    f16x8 ah[4], bh[4];
#pragma unroll
    for (int i = 0; i < 4; ++i) ah[i] = *(const f16x8*)&base[abase + i * 128];
#pragma unroll
    for (int j = 0; j < 4; ++j) bh[j] = *(const f16x8*)&pBhi[bbase + j * 128];
    if (kt + 2 < NSTEP) STAGE(kt + 2);
    __builtin_amdgcn_s_barrier();
    asm volatile("s_waitcnt lgkmcnt(0)" ::: "memory");
    __builtin_amdgcn_sched_barrier(0);
    __builtin_amdgcn_s_setprio(1);
#pragma unroll
    for (int j = 0; j < 4; ++j)
#pragma unroll
      for (int i = 0; i < 4; ++i)
        acc0[i][j] = __builtin_amdgcn_mfma_f32_16x16x32_f16(ah[i], bh[j], acc0[i][j], 0, 0, 0);
    __builtin_amdgcn_s_setprio(0);
    __builtin_amdgcn_s_barrier();
    __builtin_amdgcn_sched_barrier(0);

    // ---- P2: reads {bl x4}; 16 MFMA acc1 += ah*bl
    f16x8 bl[4];
#pragma unroll
    for (int j = 0; j < 4; ++j) bl[j] = *(const f16x8*)&pBlo[bbase + j * 128];
    __builtin_amdgcn_s_barrier();
    asm volatile("s_waitcnt lgkmcnt(0)" ::: "memory");
    __builtin_amdgcn_sched_barrier(0);
    __builtin_amdgcn_s_setprio(1);
#pragma unroll
    for (int j = 0; j < 4; ++j)
#pragma unroll
      for (int i = 0; i < 4; ++i)
        acc1[i][j] = __builtin_amdgcn_mfma_f32_16x16x32_f16(ah[i], bl[j], acc1[i][j], 0, 0, 0);
    __builtin_amdgcn_s_setprio(0);
    __builtin_amdgcn_s_barrier();
    __builtin_amdgcn_sched_barrier(0);

    // ---- P3: reads {al x4}; 16 MFMA acc1 += al*bh  (order per acc preserved)
    f16x8 al[4];
#pragma unroll
    for (int i = 0; i < 4; ++i) al[i] = *(const f16x8*)&pAlo[abase + i * 128];
    __builtin_amdgcn_s_barrier();
    asm volatile("s_waitcnt lgkmcnt(0)" ::: "memory");
    __builtin_amdgcn_sched_barrier(0);
    __builtin_amdgcn_s_setprio(1);
#pragma unroll
    for (int j = 0; j < 4; ++j)
#pragma unroll
      for (int i = 0; i < 4; ++i)
        acc1[i][j] = __builtin_amdgcn_mfma_f32_16x16x32_f16(al[i], bh[j], acc1[i][j], 0, 0, 0);
    __builtin_amdgcn_s_setprio(0);
    __builtin_amdgcn_sched_barrier(0);
    // next iteration's boundary barrier closes P3
  }
#undef STAGE

  // fused LIF epilogue
  const float DECAYF = 0.9512294245007140f;
  const float OMD = 1.0f - DECAYF;
  const float THR = 0.615f;

  float* outZ = out;
  float* outV = out + (size_t)M_DIM * N_DIM;
  const int colbase = bn * 128 + wn * 64;
  const int rowbase = bm * 256 + wm * 64 + kg * 4;

#pragma unroll
  for (int i = 0; i < 4; ++i) {
#pragma unroll
    for (int j = 0; j < 4; ++j) {
      const int col = colbase + j * 16 + lr;
#pragma unroll
      for (int r = 0; r < 4; ++r) {
        const int row = rowbase + i * 16 + r;
        const size_t idx = (size_t)row * N_DIM + col;
        const float it = acc0[i][j][r] * (1.0f / 256.0f) +
                         acc1[i][j][r] * (1.0f / 524288.0f);
        const float vv = vin[idx];
        const float zz = zin[idx];
        const float nv = DECAYF * vv + OMD * it - THR * zz;
        const float vs = (nv - THR) / THR;
        outZ[idx] = (vs > THR) ? 1.0f : 0.0f;
        outV[idx] = nv;
      }
    }
  }
}

// ---------------------------------------------------------------------------
// Fallback (round-1 monolithic kernel) — used only if ws_size < WS_NEEDED.
// ---------------------------------------------------------------------------
#define LDK 40
__global__ __launch_bounds__(256, 2) void lif_kernel(
    const float* __restrict__ inputs, const float* __restrict__ vin,
    const float* __restrict__ zin, const float* __restrict__ w_in,
    const float* __restrict__ w_rec, float* __restrict__ out) {
  __shared__ __align__(16) _Float16 sAhi[128 * LDK];
  __shared__ __align__(16) _Float16 sAlo[128 * LDK];
  __shared__ __align__(16) _Float16 sBhi[128 * LDK];
  __shared__ __align__(16) _Float16 sBlo[128 * LDK];

  const int tid = threadIdx.x;
  const int bn = blockIdx.x;
  const int bm = blockIdx.y;
  const int srow = tid & 127;
  const int skh = tid >> 7;
  const int lane = tid & 63;
  const int wid = tid >> 6;
  const int wm = wid & 1;
  const int wn = wid >> 1;
  const int lr = lane & 15;
  const int kg = lane >> 4;
  const int aoff = (wm * 64 + lr) * LDK + kg * 8;
  const int boff = (wn * 64 + lr) * LDK + kg * 8;

  f32x4 acc0[4][4];
  f32x4 acc1[4][4];
#pragma unroll
  for (int i = 0; i < 4; ++i)
#pragma unroll
    for (int j = 0; j < 4; ++j) {
      acc0[i][j] = (f32x4)0.0f;
      acc1[i][j] = (f32x4)0.0f;
    }

  const int rowg = bm * 128 + srow;
  const int ng = bn * 128 + srow;

  for (int kt = 0; kt < NSTEP; ++kt) {
    const int k0 = kt * BK;
    f16x8 ahi[2], alo[2];
    {
      const float* aptr = (k0 < KA)
          ? inputs + (size_t)rowg * KA + (k0 + skh * 16)
          : zin + (size_t)rowg * N_DIM + (k0 - KA + skh * 16);
#pragma unroll
      for (int q = 0; q < 4; ++q) {
        const float4 f = *(const float4*)(aptr + q * 4);
        const int vi = q >> 1, ei = (q & 1) * 4;
        SPLIT(f.x, ahi[vi], alo[vi], ei + 0);
        SPLIT(f.y, ahi[vi], alo[vi], ei + 1);
        SPLIT(f.z, ahi[vi], alo[vi], ei + 2);
        SPLIT(f.w, ahi[vi], alo[vi], ei + 3);
      }
    }
    f16x8 bhi[2], blo[2];
    {
      const bool isrec = (k0 >= KA);
      const int kbase = k0 - KA + skh * 16;
      const float* bptr = isrec
          ? w_rec + (size_t)kbase * N_DIM + ng
          : w_in + (size_t)(k0 + skh * 16) * N_DIM + ng;
#pragma unroll
      for (int kk = 0; kk < 16; ++kk) {
        float x = bptr[(size_t)kk * N_DIM];
        if (isrec && (kbase + kk == ng)) x = 0.0f;
        x *= 256.0f;
        SPLIT(x, bhi[kk >> 3], blo[kk >> 3], kk & 7);
      }
    }

    __syncthreads();
    {
      _Float16* pA = &sAhi[srow * LDK + skh * 16];
      *(f16x8*)(pA + 0) = ahi[0];
      *(f16x8*)(pA + 8) = ahi[1];
      _Float16* pAl = &sAlo[srow * LDK + skh * 16];
      *(f16x8*)(pAl + 0) = alo[0];
      *(f16x8*)(pAl + 8) = alo[1];
      _Float16* pB = &sBhi[srow * LDK + skh * 16];
      *(f16x8*)(pB + 0) = bhi[0];
      *(f16x8*)(pB + 8) = bhi[1];
      _Float16* pBl = &sBlo[srow * LDK + skh * 16];
      *(f16x8*)(pBl + 0) = blo[0];
      *(f16x8*)(pBl + 8) = blo[1];
    }
    __syncthreads();

    f16x8 ah[4], al[4];
#pragma unroll
    for (int i = 0; i < 4; ++i) {
      ah[i] = *(const f16x8*)&sAhi[aoff + i * 16 * LDK];
      al[i] = *(const f16x8*)&sAlo[aoff + i * 16 * LDK];
    }
#pragma unroll
    for (int j = 0; j < 4; ++j) {
      const f16x8 bh = *(const f16x8*)&sBhi[boff + j * 16 * LDK];
      const f16x8 bl = *(const f16x8*)&sBlo[boff + j * 16 * LDK];
#pragma unroll
      for (int i = 0; i < 4; ++i)
        acc0[i][j] = __builtin_amdgcn_mfma_f32_16x16x32_f16(ah[i], bh, acc0[i][j], 0, 0, 0);
#pragma unroll
      for (int i = 0; i < 4; ++i)
        acc1[i][j] = __builtin_amdgcn_mfma_f32_16x16x32_f16(ah[i], bl, acc1[i][j], 0, 0, 0);
#pragma unroll
      for (int i = 0; i < 4; ++i)
        acc1[i][j] = __builtin_amdgcn_mfma_f32_16x16x32_f16(al[i], bh, acc1[i][j], 0, 0, 0);
    }
  }

  const float DECAYF = 0.9512294245007140f;
  const float OMD = 1.0f - DECAYF;
  const float THR = 0.615f;
  float* outZ = out;
  float* outV = out + (size_t)M_DIM * N_DIM;
  const int colbase = bn * 128 + wn * 64;
  const int rowbase = bm * 128 + wm * 64 + kg * 4;
#pragma unroll
  for (int i = 0; i < 4; ++i) {
#pragma unroll
    for (int j = 0; j < 4; ++j) {
      const int col = colbase + j * 16 + lr;
#pragma unroll
      for (int r = 0; r < 4; ++r) {
        const int row = rowbase + i * 16 + r;
        const size_t idx = (size_t)row * N_DIM + col;
        const float it = acc0[i][j][r] * (1.0f / 256.0f) +
                         acc1[i][j][r] * (1.0f / 524288.0f);
        const float vv = vin[idx];
        const float zz = zin[idx];
        const float nv = DECAYF * vv + OMD * it - THR * zz;
        const float vs = (nv - THR) / THR;
        outZ[idx] = (vs > THR) ? 1.0f : 0.0f;
        outV[idx] = nv;
      }
    }
  }
}

extern "C" void kernel_launch(void* const* d_in, const int* in_sizes, int n_in,
                              void* d_out, int out_size, void* d_ws, size_t ws_size,
                              hipStream_t stream) {
  const float* inputs = (const float*)d_in[0];
  const float* v      = (const float*)d_in[1];
  const float* z      = (const float*)d_in[2];
  const float* w_in   = (const float*)d_in[3];
  const float* w_rec  = (const float*)d_in[4];
  float* out = (float*)d_out;

  if (ws_size >= WS_NEEDED) {
    _Float16* ahi = (_Float16*)d_ws;
    _Float16* alo = (_Float16*)((char*)d_ws + SZ_AH);
    _Float16* bhi = (_Float16*)((char*)d_ws + 2 * SZ_AH);
    _Float16* blo = (_Float16*)((char*)d_ws + 2 * SZ_AH + SZ_BH);

    // allow 144 KB dynamic LDS (gfx950 has 160 KB/CU); idempotent, capture-safe
    static_assert(NBUF * BUF_HALVES * sizeof(_Float16) == 147456, "LDS size");
    (void)hipFuncSetAttribute((const void*)lif_gemm,
                              hipFuncAttributeMaxDynamicSharedMemorySize, LDS_BYTES);

    hipLaunchKernelGGL(prep_ab, dim3(96, 16), dim3(256), 0, stream,
                       inputs, z, w_in, w_rec, ahi, alo, bhi, blo);
    hipLaunchKernelGGL(lif_gemm, dim3(16, 16), dim3(512), LDS_BYTES, stream,
                       ahi, alo, bhi, blo, v, z, out);
  } else {
    hipLaunchKernelGGL(lif_kernel, dim3(16, 32), dim3(256), 0, stream,
                       inputs, v, z, w_in, w_rec, out);
  }
}